// Round 2
// baseline (874.904 us; speedup 1.0000x reference)
//
#include <hip/hip_runtime.h>
#include <math.h>

#define BB   64
#define FF   1024
#define HIDD 2048
#define NHH  4
#define KSS  4
#define HDD  512
#define EPSV 1e-6f
#define INV_SQRT_HD 0.04419417382415922f  // 1/sqrt(512)

// ---------------- up GEMM: up[b,c] = sum_f inputs[b,f] * W_up[f,c] ----------------
// grid (16, 8): 256 cols per block.x, 8 b's per block.y (acc[8]/thread)
__global__ __launch_bounds__(256) void k_up(const float* __restrict__ A,
                                            const float* __restrict__ W,
                                            float* __restrict__ up) {
    const int c  = blockIdx.x * 256 + threadIdx.x;
    const int b0 = blockIdx.y * 8;
    float acc[8] = {0.f,0.f,0.f,0.f,0.f,0.f,0.f,0.f};
    const float* __restrict__ a = A + (size_t)b0 * FF;
#pragma unroll 4
    for (int f = 0; f < FF; ++f) {
        const float w = W[(size_t)f * (2*HIDD) + c];
#pragma unroll
        for (int i = 0; i < 8; ++i) acc[i] += a[(size_t)i*FF + f] * w;
    }
#pragma unroll
    for (int i = 0; i < 8; ++i) up[(size_t)(b0+i)*(2*HIDD) + c] = acc[i];
}

// ---------------- conv shift + conv + silu + blockdiag q/k/v ----------------
// grid B, block 512: thread n owns hid block [4n, 4n+4)
__global__ __launch_bounds__(512) void k_conv_qkv(
    const float* __restrict__ up, const float* __restrict__ conv_state,
    const float* __restrict__ conv_w, const float* __restrict__ conv_b,
    const float* __restrict__ Wq, const float* __restrict__ Wk, const float* __restrict__ Wv,
    float* __restrict__ out_cs, float* __restrict__ act,
    float* __restrict__ qb, float* __restrict__ kb, float* __restrict__ vb) {
    const int b  = blockIdx.x;
    const int n  = threadIdx.x;
    const int h0 = n * 4;
    const float4 x4  = *(const float4*)(up + (size_t)b*(2*HIDD) + h0);
    const float4 cs1 = *(const float4*)(conv_state + (size_t)b*KSS*HIDD + 1*HIDD + h0);
    const float4 cs2 = *(const float4*)(conv_state + (size_t)b*KSS*HIDD + 2*HIDD + h0);
    const float4 cs3 = *(const float4*)(conv_state + (size_t)b*KSS*HIDD + 3*HIDD + h0);
    *(float4*)(out_cs + (size_t)b*KSS*HIDD + 0*HIDD + h0) = cs1;
    *(float4*)(out_cs + (size_t)b*KSS*HIDD + 1*HIDD + h0) = cs2;
    *(float4*)(out_cs + (size_t)b*KSS*HIDD + 2*HIDD + h0) = cs3;
    *(float4*)(out_cs + (size_t)b*KSS*HIDD + 3*HIDD + h0) = x4;
    const float4 w0 = *(const float4*)(conv_w + 0*HIDD + h0);
    const float4 w1 = *(const float4*)(conv_w + 1*HIDD + h0);
    const float4 w2 = *(const float4*)(conv_w + 2*HIDD + h0);
    const float4 w3 = *(const float4*)(conv_w + 3*HIDD + h0);
    const float4 cb = *(const float4*)(conv_b + h0);
    float4 cx;
    cx.x = cs1.x*w0.x + cs2.x*w1.x + cs3.x*w2.x + x4.x*w3.x + cb.x;
    cx.y = cs1.y*w0.y + cs2.y*w1.y + cs3.y*w2.y + x4.y*w3.y + cb.y;
    cx.z = cs1.z*w0.z + cs2.z*w1.z + cs3.z*w2.z + x4.z*w3.z + cb.z;
    cx.w = cs1.w*w0.w + cs2.w*w1.w + cs3.w*w2.w + x4.w*w3.w + cb.w;
    float4 a4;
    a4.x = cx.x / (1.f + expf(-cx.x));
    a4.y = cx.y / (1.f + expf(-cx.y));
    a4.z = cx.z / (1.f + expf(-cx.z));
    a4.w = cx.w / (1.f + expf(-cx.w));
    *(float4*)(act + (size_t)b*HIDD + h0) = a4;

    // blockdiag: out[e] = sum_d in[d] * W[n, d, e]
    const float4 q0 = *(const float4*)(Wq + (size_t)n*16 + 0);
    const float4 q1 = *(const float4*)(Wq + (size_t)n*16 + 4);
    const float4 q2 = *(const float4*)(Wq + (size_t)n*16 + 8);
    const float4 q3 = *(const float4*)(Wq + (size_t)n*16 + 12);
    float4 q4;
    q4.x = a4.x*q0.x + a4.y*q1.x + a4.z*q2.x + a4.w*q3.x;
    q4.y = a4.x*q0.y + a4.y*q1.y + a4.z*q2.y + a4.w*q3.y;
    q4.z = a4.x*q0.z + a4.y*q1.z + a4.z*q2.z + a4.w*q3.z;
    q4.w = a4.x*q0.w + a4.y*q1.w + a4.z*q2.w + a4.w*q3.w;
    *(float4*)(qb + (size_t)b*HIDD + h0) = q4;
    const float4 k0 = *(const float4*)(Wk + (size_t)n*16 + 0);
    const float4 k1 = *(const float4*)(Wk + (size_t)n*16 + 4);
    const float4 k2 = *(const float4*)(Wk + (size_t)n*16 + 8);
    const float4 k3 = *(const float4*)(Wk + (size_t)n*16 + 12);
    float4 k4;
    k4.x = a4.x*k0.x + a4.y*k1.x + a4.z*k2.x + a4.w*k3.x;
    k4.y = a4.x*k0.y + a4.y*k1.y + a4.z*k2.y + a4.w*k3.y;
    k4.z = a4.x*k0.z + a4.y*k1.z + a4.z*k2.z + a4.w*k3.z;
    k4.w = a4.x*k0.w + a4.y*k1.w + a4.z*k2.w + a4.w*k3.w;
    *(float4*)(kb + (size_t)b*HIDD + h0) = k4;
    const float4 v0 = *(const float4*)(Wv + (size_t)n*16 + 0);
    const float4 v1 = *(const float4*)(Wv + (size_t)n*16 + 4);
    const float4 v2 = *(const float4*)(Wv + (size_t)n*16 + 8);
    const float4 v3 = *(const float4*)(Wv + (size_t)n*16 + 12);
    float4 v4;
    v4.x = x4.x*v0.x + x4.y*v1.x + x4.z*v2.x + x4.w*v3.x;
    v4.y = x4.x*v0.y + x4.y*v1.y + x4.z*v2.y + x4.w*v3.y;
    v4.z = x4.x*v0.z + x4.y*v1.z + x4.z*v2.z + x4.w*v3.z;
    v4.w = x4.x*v0.w + x4.y*v1.w + x4.z*v2.w + x4.w*v3.w;
    *(float4*)(vb + (size_t)b*HIDD + h0) = v4;
}

// ---------------- gates: i/f reductions, m_new, n_new, den ----------------
// grid B*NH, block 256
__global__ __launch_bounds__(256) void k_gates(
    const float* __restrict__ qb, const float* __restrict__ kb, const float* __restrict__ vb,
    const float* __restrict__ Wi, const float* __restrict__ bi,
    const float* __restrict__ Wf, const float* __restrict__ bf,
    const float* __restrict__ mstate_in, const float* __restrict__ nstate_in,
    float* __restrict__ out_m, float* __restrict__ out_n, float* __restrict__ scal) {
    const int bh = blockIdx.x, b = bh >> 2, h = bh & 3;
    const int tid = threadIdx.x;
    __shared__ float r1[256], r2[256];
    __shared__ float bc[3];
    float si = 0.f, sf = 0.f;
    for (int j = tid; j < 3*HIDD; j += 256) {
        const float val = (j < HIDD) ? qb[(size_t)b*HIDD + j]
                        : (j < 2*HIDD) ? kb[(size_t)b*HIDD + j - HIDD]
                                       : vb[(size_t)b*HIDD + j - 2*HIDD];
        si += val * Wi[(size_t)j*NHH + h];
        sf += val * Wf[(size_t)j*NHH + h];
    }
    r1[tid] = si; r2[tid] = sf; __syncthreads();
    for (int s = 128; s > 0; s >>= 1) {
        if (tid < s) { r1[tid] += r1[tid+s]; r2[tid] += r2[tid+s]; }
        __syncthreads();
    }
    if (tid == 0) {
        const float i_t = r1[0] + bi[h];
        const float f_t = r2[0] + bf[h];
        const float log_f = fminf(f_t, 0.f) - log1pf(expf(-fabsf(f_t)));
        const float m_old = mstate_in[bh];
        const float m_new = fmaxf(log_f + m_old, i_t);
        out_m[bh] = m_new;
        bc[0] = expf(log_f + m_old - m_new);           // f_p
        bc[1] = expf(i_t - m_new) * INV_SQRT_HD;       // i_p / sqrt(HD)
        bc[2] = expf(-m_new);
    }
    __syncthreads();
    const float f_p = bc[0], ik = bc[1];
    float qn = 0.f;
#pragma unroll
    for (int t = 0; t < 2; ++t) {
        const int d = tid + t*256;
        const float nn = f_p * nstate_in[(size_t)bh*HDD + d] + ik * kb[(size_t)b*HIDD + h*HDD + d];
        out_n[(size_t)bh*HDD + d] = nn;
        qn += qb[(size_t)b*HIDD + h*HDD + d] * nn;
    }
    __syncthreads();
    r1[tid] = qn; __syncthreads();
    for (int s = 128; s > 0; s >>= 1) {
        if (tid < s) r1[tid] += r1[tid+s];
        __syncthreads();
    }
    if (tid == 0) {
        const float den = fmaxf(fabsf(r1[0]), bc[2]);
        scal[bh*4 + 0] = f_p;
        scal[bh*4 + 1] = ik;
        scal[bh*4 + 2] = 1.f / (den + EPSV);
    }
}

// ---------------- BIG: C_new = f_p*C + ik*k[d]*v[j], nom[j] = sum_d q[d]*C_new ----------------
// grid (B*NH, 4 row-chunks of 128), block 256: tid&127 -> col4, tid>>7 -> row-half of 64
__global__ __launch_bounds__(256) void k_cupd(
    const float* __restrict__ C_in, const float* __restrict__ qb,
    const float* __restrict__ kb, const float* __restrict__ vb,
    const float* __restrict__ scal, float* __restrict__ C_out,
    float* __restrict__ nom_part) {
    const int bh = blockIdx.x, rc = blockIdx.y;
    const int b = bh >> 2, h = bh & 3;
    const int tid = threadIdx.x;
    const int c4 = tid & 127, rh = tid >> 7;
    __shared__ float qs[128], ks[128];
    if (tid < 128) qs[tid]      = qb[(size_t)b*HIDD + h*HDD + rc*128 + tid];
    else           ks[tid-128]  = kb[(size_t)b*HIDD + h*HDD + rc*128 + (tid-128)];
    __syncthreads();
    const float f_p = scal[bh*4 + 0], ik = scal[bh*4 + 1];
    const float4 v4 = *(const float4*)(vb + (size_t)b*HIDD + h*HDD + c4*4);
    float4 nom = {0.f,0.f,0.f,0.f};
    const size_t base = ((size_t)bh*HDD + rc*128 + rh*64) * HDD + c4*4;
    const float* __restrict__ cin = C_in + base;
    float* __restrict__ cout = C_out + base;
#pragma unroll 4
    for (int i = 0; i < 64; ++i) {
        const int l = rh*64 + i;
        const float4 c = *(const float4*)(cin + (size_t)i*HDD);
        const float ikk = ik * ks[l];
        float4 cn;
        cn.x = f_p*c.x + ikk*v4.x;
        cn.y = f_p*c.y + ikk*v4.y;
        cn.z = f_p*c.z + ikk*v4.z;
        cn.w = f_p*c.w + ikk*v4.w;
        *(float4*)(cout + (size_t)i*HDD) = cn;
        const float qd = qs[l];
        nom.x += qd*cn.x; nom.y += qd*cn.y; nom.z += qd*cn.z; nom.w += qd*cn.w;
    }
    __shared__ float4 rn[256];
    rn[tid] = nom;
    __syncthreads();
    if (rh == 0) {
        float4 o = rn[tid + 128];
        o.x += nom.x; o.y += nom.y; o.z += nom.z; o.w += nom.w;
        *(float4*)(nom_part + ((size_t)bh*4 + rc)*HDD + c4*4) = o;
    }
}

// ---------------- nom reduce + /den + layernorm + skip + silu(z) gate ----------------
// grid B*NH, block 256 (2 cols/thread)
__global__ __launch_bounds__(256) void k_norm(
    const float* __restrict__ nom_part, const float* __restrict__ scal,
    const float* __restrict__ norm_scale, const float* __restrict__ skip,
    const float* __restrict__ act, const float* __restrict__ up,
    float* __restrict__ hbuf) {
    const int bh = blockIdx.x, b = bh >> 2, h = bh & 3;
    const int tid = threadIdx.x;
    const float invden = scal[bh*4 + 2];
    float ht[2];
    float s = 0.f, sq = 0.f;
#pragma unroll
    for (int t = 0; t < 2; ++t) {
        const int j = tid + t*256;
        float nm = 0.f;
#pragma unroll
        for (int rc = 0; rc < 4; ++rc) nm += nom_part[((size_t)bh*4 + rc)*HDD + j];
        const float v = nm * invden;
        ht[t] = v; s += v; sq += v*v;
    }
    __shared__ float r1[256], r2[256];
    r1[tid] = s; r2[tid] = sq; __syncthreads();
    for (int st = 128; st > 0; st >>= 1) {
        if (tid < st) { r1[tid] += r1[tid+st]; r2[tid] += r2[tid+st]; }
        __syncthreads();
    }
    const float mu = r1[0] * (1.f/HDD);
    const float var = r2[0] * (1.f/HDD) - mu*mu;
    const float rs = rsqrtf(var + EPSV);
#pragma unroll
    for (int t = 0; t < 2; ++t) {
        const int j = tid + t*256;
        const int hid = h*HDD + j;
        const float hn = (ht[t] - mu) * rs * norm_scale[(size_t)h*HDD + j];
        float val = hn + skip[hid] * act[(size_t)b*HIDD + hid];
        const float z = up[(size_t)b*(2*HIDD) + HIDD + hid];
        val *= z / (1.f + expf(-z));
        hbuf[(size_t)b*HIDD + hid] = val;
    }
}

// ---------------- down GEMM: y[b,c] = sum_f h[b,f] * W_down[f,c] ----------------
// grid (4, 16): 256 cols per block.x, 4 b's per block.y
__global__ __launch_bounds__(256) void k_down(const float* __restrict__ A,
                                              const float* __restrict__ W,
                                              float* __restrict__ y) {
    const int c  = blockIdx.x * 256 + threadIdx.x;
    const int b0 = blockIdx.y * 4;
    float acc[4] = {0.f,0.f,0.f,0.f};
    const float* __restrict__ a = A + (size_t)b0 * HIDD;
#pragma unroll 4
    for (int f = 0; f < HIDD; ++f) {
        const float w = W[(size_t)f*FF + c];
#pragma unroll
        for (int i = 0; i < 4; ++i) acc[i] += a[(size_t)i*HIDD + f] * w;
    }
#pragma unroll
    for (int i = 0; i < 4; ++i) y[(size_t)(b0+i)*FF + c] = acc[i];
}

extern "C" void kernel_launch(void* const* d_in, const int* in_sizes, int n_in,
                              void* d_out, int out_size, void* d_ws, size_t ws_size,
                              hipStream_t stream) {
    const float* inputs     = (const float*)d_in[0];
    const float* C_in       = (const float*)d_in[1];
    const float* nstate_in  = (const float*)d_in[2];
    const float* mstate_in  = (const float*)d_in[3];
    const float* conv_state = (const float*)d_in[4];
    const float* W_up       = (const float*)d_in[5];
    const float* conv_w     = (const float*)d_in[6];
    const float* conv_b     = (const float*)d_in[7];
    const float* Wq         = (const float*)d_in[8];
    const float* Wk         = (const float*)d_in[9];
    const float* Wv         = (const float*)d_in[10];
    const float* Wi         = (const float*)d_in[11];
    const float* bi         = (const float*)d_in[12];
    const float* Wf         = (const float*)d_in[13];
    const float* bf         = (const float*)d_in[14];
    const float* norm_scale = (const float*)d_in[15];
    const float* skip       = (const float*)d_in[16];
    const float* W_down     = (const float*)d_in[17];

    float* ws = (float*)d_ws;
    float* up       = ws;                 // 64*4096        = 262144
    float* act      = ws + 262144;        // 64*2048        = 131072
    float* qb       = ws + 393216;        // 131072
    float* kb       = ws + 524288;        // 131072
    float* vb       = ws + 655360;        // 131072
    float* scal     = ws + 786432;        // 256*4          = 1024
    float* nom_part = ws + 787456;        // 256*4*512      = 524288
    float* hbuf     = ws + 1311744;       // 131072  (total 1442816 floats = 5.6 MB)

    float* out_y  = (float*)d_out;        // 65536
    float* out_C  = out_y + 65536;        // 67108864
    float* out_n  = out_C + 67108864;     // 131072
    float* out_m  = out_n + 131072;       // 256
    float* out_cs = out_m + 256;          // 524288

    k_up      <<<dim3(16, 8),  256, 0, stream>>>(inputs, W_up, up);
    k_conv_qkv<<<BB,           512, 0, stream>>>(up, conv_state, conv_w, conv_b,
                                                 Wq, Wk, Wv, out_cs, act, qb, kb, vb);
    k_gates   <<<BB*NHH,       256, 0, stream>>>(qb, kb, vb, Wi, bi, Wf, bf,
                                                 mstate_in, nstate_in, out_m, out_n, scal);
    k_cupd    <<<dim3(BB*NHH, 4), 256, 0, stream>>>(C_in, qb, kb, vb, scal, out_C, nom_part);
    k_norm    <<<BB*NHH,       256, 0, stream>>>(nom_part, scal, norm_scale, skip, act, up, hbuf);
    k_down    <<<dim3(4, 16),  256, 0, stream>>>(hbuf, W_down, out_y);
}

// Round 3
// 579.761 us; speedup vs baseline: 1.5091x; 1.5091x over previous
//
#include <hip/hip_runtime.h>
#include <math.h>

#define BB   64
#define FF   1024
#define HIDD 2048
#define NHH  4
#define KSS  4
#define HDD  512
#define EPSV 1e-6f
#define INV_SQRT_HD 0.04419417382415922f  // 1/sqrt(512)

// ---------------- up GEMM split-K: part[kc][b][c] = sum_{f in chunk} A[b,f]*W[f,c] ----------------
// grid (16 coltiles, 4 btiles, 4 kchunks) = 256 blocks, block 256.
// btile=16, kchunk=256. LDS A-tile 16x256. 16 FMA per coalesced 4B weight load.
__global__ __launch_bounds__(256) void k_up_part(const float* __restrict__ A,
                                                 const float* __restrict__ W,
                                                 float* __restrict__ part) {
    const int tid = threadIdx.x;
    const int c  = blockIdx.x * 256 + tid;
    const int b0 = blockIdx.y * 16;
    const int k0 = blockIdx.z * 256;
    __shared__ float As[16 * 256];
#pragma unroll
    for (int j = 0; j < 16; ++j)
        As[j * 256 + tid] = A[(size_t)(b0 + j) * FF + k0 + tid];
    __syncthreads();
    float acc[16];
#pragma unroll
    for (int i = 0; i < 16; ++i) acc[i] = 0.f;
    const float* __restrict__ wp = W + (size_t)k0 * (2 * HIDD) + c;
#pragma unroll 4
    for (int f = 0; f < 256; ++f) {
        const float w = wp[(size_t)f * (2 * HIDD)];
#pragma unroll
        for (int i = 0; i < 16; ++i) acc[i] += As[i * 256 + f] * w;
    }
    float* __restrict__ pp = part + ((size_t)blockIdx.z * BB + b0) * (2 * HIDD) + c;
#pragma unroll
    for (int i = 0; i < 16; ++i) pp[(size_t)i * (2 * HIDD)] = acc[i];
}

// reduce 4 partials -> up. grid 256, block 256, float4 (262144 floats / 1024 per block)
__global__ __launch_bounds__(256) void k_up_red(const float* __restrict__ part,
                                                float* __restrict__ up) {
    const int i = (blockIdx.x * 256 + threadIdx.x) * 4;
    float4 s = *(const float4*)(part + i);
#pragma unroll
    for (int kc = 1; kc < 4; ++kc) {
        const float4 p = *(const float4*)(part + (size_t)kc * BB * 2 * HIDD + i);
        s.x += p.x; s.y += p.y; s.z += p.z; s.w += p.w;
    }
    *(float4*)(up + i) = s;
}

// ---------------- conv shift + conv + silu + blockdiag q/k/v ----------------
__global__ __launch_bounds__(512) void k_conv_qkv(
    const float* __restrict__ up, const float* __restrict__ conv_state,
    const float* __restrict__ conv_w, const float* __restrict__ conv_b,
    const float* __restrict__ Wq, const float* __restrict__ Wk, const float* __restrict__ Wv,
    float* __restrict__ out_cs, float* __restrict__ act,
    float* __restrict__ qb, float* __restrict__ kb, float* __restrict__ vb) {
    const int b  = blockIdx.x;
    const int n  = threadIdx.x;
    const int h0 = n * 4;
    const float4 x4  = *(const float4*)(up + (size_t)b*(2*HIDD) + h0);
    const float4 cs1 = *(const float4*)(conv_state + (size_t)b*KSS*HIDD + 1*HIDD + h0);
    const float4 cs2 = *(const float4*)(conv_state + (size_t)b*KSS*HIDD + 2*HIDD + h0);
    const float4 cs3 = *(const float4*)(conv_state + (size_t)b*KSS*HIDD + 3*HIDD + h0);
    *(float4*)(out_cs + (size_t)b*KSS*HIDD + 0*HIDD + h0) = cs1;
    *(float4*)(out_cs + (size_t)b*KSS*HIDD + 1*HIDD + h0) = cs2;
    *(float4*)(out_cs + (size_t)b*KSS*HIDD + 2*HIDD + h0) = cs3;
    *(float4*)(out_cs + (size_t)b*KSS*HIDD + 3*HIDD + h0) = x4;
    const float4 w0 = *(const float4*)(conv_w + 0*HIDD + h0);
    const float4 w1 = *(const float4*)(conv_w + 1*HIDD + h0);
    const float4 w2 = *(const float4*)(conv_w + 2*HIDD + h0);
    const float4 w3 = *(const float4*)(conv_w + 3*HIDD + h0);
    const float4 cb = *(const float4*)(conv_b + h0);
    float4 cx;
    cx.x = cs1.x*w0.x + cs2.x*w1.x + cs3.x*w2.x + x4.x*w3.x + cb.x;
    cx.y = cs1.y*w0.y + cs2.y*w1.y + cs3.y*w2.y + x4.y*w3.y + cb.y;
    cx.z = cs1.z*w0.z + cs2.z*w1.z + cs3.z*w2.z + x4.z*w3.z + cb.z;
    cx.w = cs1.w*w0.w + cs2.w*w1.w + cs3.w*w2.w + x4.w*w3.w + cb.w;
    float4 a4;
    a4.x = cx.x / (1.f + expf(-cx.x));
    a4.y = cx.y / (1.f + expf(-cx.y));
    a4.z = cx.z / (1.f + expf(-cx.z));
    a4.w = cx.w / (1.f + expf(-cx.w));
    *(float4*)(act + (size_t)b*HIDD + h0) = a4;

    const float4 q0 = *(const float4*)(Wq + (size_t)n*16 + 0);
    const float4 q1 = *(const float4*)(Wq + (size_t)n*16 + 4);
    const float4 q2 = *(const float4*)(Wq + (size_t)n*16 + 8);
    const float4 q3 = *(const float4*)(Wq + (size_t)n*16 + 12);
    float4 q4;
    q4.x = a4.x*q0.x + a4.y*q1.x + a4.z*q2.x + a4.w*q3.x;
    q4.y = a4.x*q0.y + a4.y*q1.y + a4.z*q2.y + a4.w*q3.y;
    q4.z = a4.x*q0.z + a4.y*q1.z + a4.z*q2.z + a4.w*q3.z;
    q4.w = a4.x*q0.w + a4.y*q1.w + a4.z*q2.w + a4.w*q3.w;
    *(float4*)(qb + (size_t)b*HIDD + h0) = q4;
    const float4 k0 = *(const float4*)(Wk + (size_t)n*16 + 0);
    const float4 k1 = *(const float4*)(Wk + (size_t)n*16 + 4);
    const float4 k2 = *(const float4*)(Wk + (size_t)n*16 + 8);
    const float4 k3 = *(const float4*)(Wk + (size_t)n*16 + 12);
    float4 k4;
    k4.x = a4.x*k0.x + a4.y*k1.x + a4.z*k2.x + a4.w*k3.x;
    k4.y = a4.x*k0.y + a4.y*k1.y + a4.z*k2.y + a4.w*k3.y;
    k4.z = a4.x*k0.z + a4.y*k1.z + a4.z*k2.z + a4.w*k3.z;
    k4.w = a4.x*k0.w + a4.y*k1.w + a4.z*k2.w + a4.w*k3.w;
    *(float4*)(kb + (size_t)b*HIDD + h0) = k4;
    const float4 v0 = *(const float4*)(Wv + (size_t)n*16 + 0);
    const float4 v1 = *(const float4*)(Wv + (size_t)n*16 + 4);
    const float4 v2 = *(const float4*)(Wv + (size_t)n*16 + 8);
    const float4 v3 = *(const float4*)(Wv + (size_t)n*16 + 12);
    float4 v4;
    v4.x = x4.x*v0.x + x4.y*v1.x + x4.z*v2.x + x4.w*v3.x;
    v4.y = x4.x*v0.y + x4.y*v1.y + x4.z*v2.y + x4.w*v3.y;
    v4.z = x4.x*v0.z + x4.y*v1.z + x4.z*v2.z + x4.w*v3.z;
    v4.w = x4.x*v0.w + x4.y*v1.w + x4.z*v2.w + x4.w*v3.w;
    *(float4*)(vb + (size_t)b*HIDD + h0) = v4;
}

// ---------------- gates: i/f reductions, m_new, n_new, den ----------------
__global__ __launch_bounds__(256) void k_gates(
    const float* __restrict__ qb, const float* __restrict__ kb, const float* __restrict__ vb,
    const float* __restrict__ Wi, const float* __restrict__ bi,
    const float* __restrict__ Wf, const float* __restrict__ bf,
    const float* __restrict__ mstate_in, const float* __restrict__ nstate_in,
    float* __restrict__ out_m, float* __restrict__ out_n, float* __restrict__ scal) {
    const int bh = blockIdx.x, b = bh >> 2, h = bh & 3;
    const int tid = threadIdx.x;
    __shared__ float r1[256], r2[256];
    __shared__ float bc[3];
    float si = 0.f, sf = 0.f;
    for (int j = tid; j < 3*HIDD; j += 256) {
        const float val = (j < HIDD) ? qb[(size_t)b*HIDD + j]
                        : (j < 2*HIDD) ? kb[(size_t)b*HIDD + j - HIDD]
                                       : vb[(size_t)b*HIDD + j - 2*HIDD];
        si += val * Wi[(size_t)j*NHH + h];
        sf += val * Wf[(size_t)j*NHH + h];
    }
    r1[tid] = si; r2[tid] = sf; __syncthreads();
    for (int s = 128; s > 0; s >>= 1) {
        if (tid < s) { r1[tid] += r1[tid+s]; r2[tid] += r2[tid+s]; }
        __syncthreads();
    }
    if (tid == 0) {
        const float i_t = r1[0] + bi[h];
        const float f_t = r2[0] + bf[h];
        const float log_f = fminf(f_t, 0.f) - log1pf(expf(-fabsf(f_t)));
        const float m_old = mstate_in[bh];
        const float m_new = fmaxf(log_f + m_old, i_t);
        out_m[bh] = m_new;
        bc[0] = expf(log_f + m_old - m_new);           // f_p
        bc[1] = expf(i_t - m_new) * INV_SQRT_HD;       // i_p / sqrt(HD)
        bc[2] = expf(-m_new);
    }
    __syncthreads();
    const float f_p = bc[0], ik = bc[1];
    float qn = 0.f;
#pragma unroll
    for (int t = 0; t < 2; ++t) {
        const int d = tid + t*256;
        const float nn = f_p * nstate_in[(size_t)bh*HDD + d] + ik * kb[(size_t)b*HIDD + h*HDD + d];
        out_n[(size_t)bh*HDD + d] = nn;
        qn += qb[(size_t)b*HIDD + h*HDD + d] * nn;
    }
    __syncthreads();
    r1[tid] = qn; __syncthreads();
    for (int s = 128; s > 0; s >>= 1) {
        if (tid < s) r1[tid] += r1[tid+s];
        __syncthreads();
    }
    if (tid == 0) {
        const float den = fmaxf(fabsf(r1[0]), bc[2]);
        scal[bh*4 + 0] = f_p;
        scal[bh*4 + 1] = ik;
        scal[bh*4 + 2] = 1.f / (den + EPSV);
    }
}

// ---------------- BIG: C_new = f_p*C + ik*k[d]*v[j], nom[j] = sum_d q[d]*C_new ----------------
__global__ __launch_bounds__(256) void k_cupd(
    const float* __restrict__ C_in, const float* __restrict__ qb,
    const float* __restrict__ kb, const float* __restrict__ vb,
    const float* __restrict__ scal, float* __restrict__ C_out,
    float* __restrict__ nom_part) {
    const int bh = blockIdx.x, rc = blockIdx.y;
    const int b = bh >> 2, h = bh & 3;
    const int tid = threadIdx.x;
    const int c4 = tid & 127, rh = tid >> 7;
    __shared__ float qs[128], ks[128];
    if (tid < 128) qs[tid]      = qb[(size_t)b*HIDD + h*HDD + rc*128 + tid];
    else           ks[tid-128]  = kb[(size_t)b*HIDD + h*HDD + rc*128 + (tid-128)];
    __syncthreads();
    const float f_p = scal[bh*4 + 0], ik = scal[bh*4 + 1];
    const float4 v4 = *(const float4*)(vb + (size_t)b*HIDD + h*HDD + c4*4);
    float4 nom = {0.f,0.f,0.f,0.f};
    const size_t base = ((size_t)bh*HDD + rc*128 + rh*64) * HDD + c4*4;
    const float* __restrict__ cin = C_in + base;
    float* __restrict__ cout = C_out + base;
#pragma unroll 4
    for (int i = 0; i < 64; ++i) {
        const int l = rh*64 + i;
        const float4 c = *(const float4*)(cin + (size_t)i*HDD);
        const float ikk = ik * ks[l];
        float4 cn;
        cn.x = f_p*c.x + ikk*v4.x;
        cn.y = f_p*c.y + ikk*v4.y;
        cn.z = f_p*c.z + ikk*v4.z;
        cn.w = f_p*c.w + ikk*v4.w;
        *(float4*)(cout + (size_t)i*HDD) = cn;
        const float qd = qs[l];
        nom.x += qd*cn.x; nom.y += qd*cn.y; nom.z += qd*cn.z; nom.w += qd*cn.w;
    }
    __shared__ float4 rn[256];
    rn[tid] = nom;
    __syncthreads();
    if (rh == 0) {
        float4 o = rn[tid + 128];
        o.x += nom.x; o.y += nom.y; o.z += nom.z; o.w += nom.w;
        *(float4*)(nom_part + ((size_t)bh*4 + rc)*HDD + c4*4) = o;
    }
}

// ---------------- nom reduce + /den + layernorm + skip + silu(z) gate ----------------
__global__ __launch_bounds__(256) void k_norm(
    const float* __restrict__ nom_part, const float* __restrict__ scal,
    const float* __restrict__ norm_scale, const float* __restrict__ skip,
    const float* __restrict__ act, const float* __restrict__ up,
    float* __restrict__ hbuf) {
    const int bh = blockIdx.x, b = bh >> 2, h = bh & 3;
    const int tid = threadIdx.x;
    const float invden = scal[bh*4 + 2];
    float ht[2];
    float s = 0.f, sq = 0.f;
#pragma unroll
    for (int t = 0; t < 2; ++t) {
        const int j = tid + t*256;
        float nm = 0.f;
#pragma unroll
        for (int rc = 0; rc < 4; ++rc) nm += nom_part[((size_t)bh*4 + rc)*HDD + j];
        const float v = nm * invden;
        ht[t] = v; s += v; sq += v*v;
    }
    __shared__ float r1[256], r2[256];
    r1[tid] = s; r2[tid] = sq; __syncthreads();
    for (int st = 128; st > 0; st >>= 1) {
        if (tid < st) { r1[tid] += r1[tid+st]; r2[tid] += r2[tid+st]; }
        __syncthreads();
    }
    const float mu = r1[0] * (1.f/HDD);
    const float var = r2[0] * (1.f/HDD) - mu*mu;
    const float rs = rsqrtf(var + EPSV);
#pragma unroll
    for (int t = 0; t < 2; ++t) {
        const int j = tid + t*256;
        const int hid = h*HDD + j;
        const float hn = (ht[t] - mu) * rs * norm_scale[(size_t)h*HDD + j];
        float val = hn + skip[hid] * act[(size_t)b*HIDD + hid];
        const float z = up[(size_t)b*(2*HIDD) + HIDD + hid];
        val *= z / (1.f + expf(-z));
        hbuf[(size_t)b*HIDD + hid] = val;
    }
}

// ---------------- down GEMM split-K: part[kc][b][c], btile=16, kchunk=128 ----------------
// grid (4 coltiles, 4 btiles, 16 kchunks) = 256 blocks, block 256.
__global__ __launch_bounds__(256) void k_down_part(const float* __restrict__ A,
                                                   const float* __restrict__ W,
                                                   float* __restrict__ part) {
    const int tid = threadIdx.x;
    const int c  = blockIdx.x * 256 + tid;
    const int b0 = blockIdx.y * 16;
    const int k0 = blockIdx.z * 128;
    __shared__ float As[16 * 128];
#pragma unroll
    for (int j = 0; j < 8; ++j) {
        const int e = j * 256 + tid;
        const int i = e >> 7, f = e & 127;
        As[e] = A[(size_t)(b0 + i) * HIDD + k0 + f];
    }
    __syncthreads();
    float acc[16];
#pragma unroll
    for (int i = 0; i < 16; ++i) acc[i] = 0.f;
    const float* __restrict__ wp = W + (size_t)k0 * FF + c;
#pragma unroll 4
    for (int f = 0; f < 128; ++f) {
        const float w = wp[(size_t)f * FF];
#pragma unroll
        for (int i = 0; i < 16; ++i) acc[i] += As[i * 128 + f] * w;
    }
    float* __restrict__ pp = part + ((size_t)blockIdx.z * BB + b0) * FF + c;
#pragma unroll
    for (int i = 0; i < 16; ++i) pp[(size_t)i * FF] = acc[i];
}

// reduce 16 partials -> y. grid 64, block 256, float4 (65536 floats)
__global__ __launch_bounds__(256) void k_down_red(const float* __restrict__ part,
                                                  float* __restrict__ y) {
    const int i = (blockIdx.x * 256 + threadIdx.x) * 4;
    float4 s = *(const float4*)(part + i);
#pragma unroll
    for (int kc = 1; kc < 16; ++kc) {
        const float4 p = *(const float4*)(part + (size_t)kc * BB * FF + i);
        s.x += p.x; s.y += p.y; s.z += p.z; s.w += p.w;
    }
    *(float4*)(y + i) = s;
}

extern "C" void kernel_launch(void* const* d_in, const int* in_sizes, int n_in,
                              void* d_out, int out_size, void* d_ws, size_t ws_size,
                              hipStream_t stream) {
    const float* inputs     = (const float*)d_in[0];
    const float* C_in       = (const float*)d_in[1];
    const float* nstate_in  = (const float*)d_in[2];
    const float* mstate_in  = (const float*)d_in[3];
    const float* conv_state = (const float*)d_in[4];
    const float* W_up       = (const float*)d_in[5];
    const float* conv_w     = (const float*)d_in[6];
    const float* conv_b     = (const float*)d_in[7];
    const float* Wq         = (const float*)d_in[8];
    const float* Wk         = (const float*)d_in[9];
    const float* Wv         = (const float*)d_in[10];
    const float* Wi         = (const float*)d_in[11];
    const float* bi         = (const float*)d_in[12];
    const float* Wf         = (const float*)d_in[13];
    const float* bf         = (const float*)d_in[14];
    const float* norm_scale = (const float*)d_in[15];
    const float* skip       = (const float*)d_in[16];
    const float* W_down     = (const float*)d_in[17];

    float* ws = (float*)d_ws;
    float* up       = ws;                 // 262144
    float* act      = ws + 262144;        // 131072
    float* qb       = ws + 393216;        // 131072
    float* kb       = ws + 524288;        // 131072
    float* vb       = ws + 655360;        // 131072
    float* scal     = ws + 786432;        // 1024
    float* nom_part = ws + 787456;        // 524288
    float* hbuf     = ws + 1311744;       // 131072
    float* part_up  = ws + 1442816;       // 4*64*4096 = 1048576
    float* part_y   = ws + 2491392;       // 16*64*1024 = 1048576  (total 3539968 fl = 14.2 MB)

    float* out_y  = (float*)d_out;        // 65536
    float* out_C  = out_y + 65536;        // 67108864
    float* out_n  = out_C + 67108864;     // 131072
    float* out_m  = out_n + 131072;       // 256
    float* out_cs = out_m + 256;          // 524288

    k_up_part <<<dim3(16, 4, 4), 256, 0, stream>>>(inputs, W_up, part_up);
    k_up_red  <<<256,            256, 0, stream>>>(part_up, up);
    k_conv_qkv<<<BB,             512, 0, stream>>>(up, conv_state, conv_w, conv_b,
                                                   Wq, Wk, Wv, out_cs, act, qb, kb, vb);
    k_gates   <<<BB*NHH,         256, 0, stream>>>(qb, kb, vb, Wi, bi, Wf, bf,
                                                   mstate_in, nstate_in, out_m, out_n, scal);
    k_cupd    <<<dim3(BB*NHH, 4), 256, 0, stream>>>(C_in, qb, kb, vb, scal, out_C, nom_part);
    k_norm    <<<BB*NHH,         256, 0, stream>>>(nom_part, scal, norm_scale, skip, act, up, hbuf);
    k_down_part<<<dim3(4, 4, 16), 256, 0, stream>>>(hbuf, W_down, part_y);
    k_down_red <<<64,            256, 0, stream>>>(part_y, out_y);
}